// Round 2
// baseline (558.012 us; speedup 1.0000x reference)
//
#include <hip/hip_runtime.h>
#include <cstdint>
#include <cstddef>

using u32 = unsigned int;
using u64 = unsigned long long;

constexpr int BATCH = 2;
constexpr int N0 = 8192;
constexpr int N1 = 4096;
constexpr int N2 = 2048;
constexpr int CIN = 64;
constexpr int COUT = 128;
constexpr int KNB = 16;   // neighbors

// -------- prep: fp32 positions -> padded float4 arrays; emit pos output (exact copy) --------
__global__ __launch_bounds__(256)
void prep_kernel(const float* __restrict__ pos0, float4* __restrict__ pos0f,
                 float4* __restrict__ pos1f, float* __restrict__ pos_out) {
    int i = blockIdx.x * 256 + threadIdx.x;
    if (i >= BATCH * N0) return;
    int b = i >> 13;
    int n = i & (N0 - 1);
    const float* s = pos0 + (size_t)i * 3;
    float4 v = make_float4(s[0], s[1], s[2], 0.f);
    pos0f[i] = v;
    if (!(n & 1)) pos1f[b * N1 + (n >> 1)] = v;
    if (!(n & 3)) {
        float* d = pos_out + ((size_t)b * N2 + (n >> 2)) * 3;
        d[0] = s[0]; d[1] = s[1]; d[2] = s[2];
    }
}

// Distances must match the np reference bit-exactly: no FMA contraction, sequential sum.
__device__ __forceinline__ float dist2(float4 a, float4 p) {
#pragma clang fp contract(off)
    float dx = a.x - p.x;
    float dy = a.y - p.y;
    float dz = a.z - p.z;
    float s = dx * dx;
    s = s + dy * dy;
    s = s + dz * dz;
    return s;
}

// -------- KNN: one wave (64 lanes) per center; replicated sorted-16 list of u64 keys --------
__global__ __launch_bounds__(256)
void knn_kernel(const float4* __restrict__ pts, int npts, int nctr, int stride,
                int* __restrict__ out) {
    int wave = (blockIdx.x * blockDim.x + threadIdx.x) >> 6;
    int lane = threadIdx.x & 63;
    int b = wave / nctr;
    int j = wave - b * nctr;
    const float4* P = pts + (size_t)b * npts;
    float4 c = P[j * stride];

    u64 key[16];
    // warm start: bitonic-sort first 64 points across lanes, broadcast best 16
    {
        float4 p = P[lane];
        float d = dist2(c, p);
        u64 k = (((u64)__float_as_uint(d)) << 32) | (u32)lane;
#pragma unroll
        for (int kk = 2; kk <= 64; kk <<= 1) {
#pragma unroll
            for (int jj = kk >> 1; jj > 0; jj >>= 1) {
                u64 o = __shfl_xor(k, jj, 64);
                bool keepmin = (((lane & jj) == 0) == ((lane & kk) == 0));
                if (keepmin) k = (o < k) ? o : k;
                else         k = (o > k) ? o : k;
            }
        }
#pragma unroll
        for (int t = 0; t < 16; ++t) key[t] = __shfl(k, t, 64);
    }

    int nstep = npts >> 6;
    for (int s = 1; s < nstep; ++s) {
        int i = (s << 6) + lane;
        float4 p = P[i];
        float d = dist2(c, p);
        u64 k = (((u64)__float_as_uint(d)) << 32) | (u32)i;
        u64 ball = __ballot(k < key[15]);
        while (ball) {
            int src = __ffsll(ball) - 1;
            ball &= ball - 1;
            u64 nk = __shfl(k, src, 64);
            // branchless shift-insert (no-op if nk >= key[15])
#pragma unroll
            for (int t = 15; t > 0; --t) {
                bool ltc = nk < key[t];
                bool ltp = nk < key[t - 1];
                key[t] = ltc ? (ltp ? key[t - 1] : nk) : key[t];
            }
            key[0] = (nk < key[0]) ? nk : key[0];
        }
    }
    if (lane == 0) {
        int* o = out + ((size_t)(b * nctr + j)) * KNB;
#pragma unroll
        for (int t = 0; t < 16; ++t) o[t] = (int)(u32)key[t];
    }
}

// -------- conv1: gathered GEMM K=1024 + bias + LN + SiLU -> ch1; residual matmul -> res1 --------
__global__ __launch_bounds__(256)
void conv1_kernel(const float* __restrict__ ch0, const int* __restrict__ knn1,
                  const float* __restrict__ W1, const float* __restrict__ b1,
                  const float* __restrict__ Wres, const float* __restrict__ bres,
                  const float* __restrict__ g1, const float* __restrict__ be1,
                  float* __restrict__ ch1, float* __restrict__ res1) {
    __shared__ float A[8][1024];     // gathered channels, 32 KB
    __shared__ float Wt[32][132];    // W1^T chunk [kc][o], padded, 16.9 KB
    __shared__ float CRow[8][64];    // center rows for residual, 2 KB
    __shared__ int knnr[8][16];
    __shared__ float cb1[128], cg1[128], cbe1[128], cbr[128];

    int tid = threadIdx.x;
    int blk = blockIdx.x;            // 1024 blocks, 512 per batch
    int b = blk >> 9;
    int g = blk & 511;
    int jbase = g * 8;

    if (tid < 128) {
        cb1[tid] = b1[tid]; cg1[tid] = g1[tid]; cbe1[tid] = be1[tid]; cbr[tid] = bres[tid];
        int cc = tid >> 4, k = tid & 15;
        knnr[cc][k] = knn1[((size_t)(b * N1 + jbase + cc)) * KNB + k];
    }
    __syncthreads();
    {   // gather A: 128 rows of 256B, 2 threads per row
        int row = tid >> 1, half = tid & 1;
        int cc = row >> 4, k = row & 15;
        const float4* src = (const float4*)(ch0 + ((size_t)(b * N0 + knnr[cc][k])) * CIN + half * 32);
        float4* dst = (float4*)&A[cc][k * 64 + half * 32];
#pragma unroll
        for (int q = 0; q < 8; ++q) dst[q] = src[q];
    }
    if (tid < 128) {  // center rows (level-0 idx = 2*j)
        int cc = tid >> 4, part = tid & 15;
        const float4* src = (const float4*)(ch0 + ((size_t)(b * N0 + 2 * (jbase + cc))) * CIN + part * 4);
        *(float4*)&CRow[cc][part * 4] = *src;
    }
    __syncthreads();

    int cc = tid >> 5, og = tid & 31;   // 8 centers x 32 o-groups (4 outputs each)
    float acc[4] = {0.f, 0.f, 0.f, 0.f};

    for (int chunk = 0; chunk < 32; ++chunk) {   // K = 32*32
        {   // stage transposed W chunk: kc in [chunk*32, chunk*32+32)
            int o = tid >> 1, half = tid & 1;
            const float4* src = (const float4*)(W1 + (size_t)o * 1024 + chunk * 32 + half * 16);
#pragma unroll
            for (int q = 0; q < 4; ++q) {
                float4 v = src[q];
                int kc = half * 16 + q * 4;
                Wt[kc + 0][o] = v.x; Wt[kc + 1][o] = v.y;
                Wt[kc + 2][o] = v.z; Wt[kc + 3][o] = v.w;
            }
        }
        __syncthreads();
        const float* Arow = &A[cc][chunk * 32];
#pragma unroll
        for (int k4 = 0; k4 < 8; ++k4) {
            float4 a4 = *(const float4*)(Arow + k4 * 4);
            float av[4] = {a4.x, a4.y, a4.z, a4.w};
#pragma unroll
            for (int e = 0; e < 4; ++e) {
                float4 w = *(const float4*)&Wt[k4 * 4 + e][og * 4];
                acc[0] = fmaf(av[e], w.x, acc[0]);
                acc[1] = fmaf(av[e], w.y, acc[1]);
                acc[2] = fmaf(av[e], w.z, acc[2]);
                acc[3] = fmaf(av[e], w.w, acc[3]);
            }
        }
        __syncthreads();
    }

    // bias + LN (shfl reduction over the 32-lane og-group)
    float x[4], s = 0.f, ss = 0.f;
#pragma unroll
    for (int u = 0; u < 4; ++u) {
        x[u] = acc[u] + cb1[og * 4 + u];
        s += x[u]; ss += x[u] * x[u];
    }
#pragma unroll
    for (int off = 16; off > 0; off >>= 1) {
        s += __shfl_xor(s, off, 32);
        ss += __shfl_xor(ss, off, 32);
    }
    float mu = s * (1.f / 128.f);
    float var = fmaxf(ss * (1.f / 128.f) - mu * mu, 0.f);
    float rs = 1.f / sqrtf(var + 1e-5f);
    int j = jbase + cc;
    float4 outv;
    float* ov = &outv.x;
#pragma unroll
    for (int u = 0; u < 4; ++u) {
        int o = og * 4 + u;
        float y = (x[u] - mu) * rs * cg1[o] + cbe1[o];
        ov[u] = y / (1.f + __expf(-y));
    }
    *(float4*)(ch1 + ((size_t)(b * N1 + j)) * COUT + og * 4) = outv;

    // residual: CRow @ Wres + bres (fp32)
    float r[4] = {cbr[og * 4], cbr[og * 4 + 1], cbr[og * 4 + 2], cbr[og * 4 + 3]};
    for (int c2 = 0; c2 < 64; ++c2) {
        float a = CRow[cc][c2];
        float4 w = *(const float4*)(Wres + (size_t)c2 * COUT + og * 4);
        r[0] = fmaf(a, w.x, r[0]); r[1] = fmaf(a, w.y, r[1]);
        r[2] = fmaf(a, w.z, r[2]); r[3] = fmaf(a, w.w, r[3]);
    }
    *(float4*)(res1 + ((size_t)(b * N1 + j)) * COUT + og * 4) = make_float4(r[0], r[1], r[2], r[3]);
}

// -------- conv2: gathered GEMM K=2048 + bias + LN + SiLU + res-add -> fp32 output --------
__global__ __launch_bounds__(256)
void conv2_kernel(const float* __restrict__ ch1, const int* __restrict__ knn2,
                  const float* __restrict__ W2, const float* __restrict__ b2,
                  const float* __restrict__ g2, const float* __restrict__ be2,
                  const float* __restrict__ res1, float* __restrict__ ch_out) {
    __shared__ float A[4][2048];     // 32 KB
    __shared__ float Wt[32][132];    // 16.9 KB
    __shared__ int knnr[4][16];
    __shared__ float cb[128], cg[128], cbe[128];

    int tid = threadIdx.x;
    int blk = blockIdx.x;            // 1024 blocks, 512 per batch
    int b = blk >> 9;
    int g = blk & 511;
    int ibase = g * 4;

    if (tid < 128) { cb[tid] = b2[tid]; cg[tid] = g2[tid]; cbe[tid] = be2[tid]; }
    if (tid < 64) {
        int cc = tid >> 4, k = tid & 15;
        knnr[cc][k] = knn2[((size_t)(b * N2 + ibase + cc)) * KNB + k];
    }
    __syncthreads();
    {   // gather A: 64 rows of 512B, 4 threads per row
        int row = tid >> 2, q = tid & 3;
        int cc = row >> 4, k = row & 15;
        const float4* src = (const float4*)(ch1 + ((size_t)(b * N1 + knnr[cc][k])) * COUT + q * 32);
        float4* dst = (float4*)&A[cc][k * 128 + q * 32];
#pragma unroll
        for (int p = 0; p < 8; ++p) dst[p] = src[p];
    }
    __syncthreads();

    int cc = tid >> 6, og = tid & 63;   // 4 centers x 64 o-groups (2 outputs each)
    float acc0 = 0.f, acc1 = 0.f;
    for (int chunk = 0; chunk < 64; ++chunk) {   // K = 64*32
        {
            int o = tid >> 1, half = tid & 1;
            const float4* src = (const float4*)(W2 + (size_t)o * 2048 + chunk * 32 + half * 16);
#pragma unroll
            for (int q = 0; q < 4; ++q) {
                float4 v = src[q];
                int kc = half * 16 + q * 4;
                Wt[kc + 0][o] = v.x; Wt[kc + 1][o] = v.y;
                Wt[kc + 2][o] = v.z; Wt[kc + 3][o] = v.w;
            }
        }
        __syncthreads();
        const float* Arow = &A[cc][chunk * 32];
#pragma unroll
        for (int k4 = 0; k4 < 8; ++k4) {
            float4 a4 = *(const float4*)(Arow + k4 * 4);
            float av[4] = {a4.x, a4.y, a4.z, a4.w};
#pragma unroll
            for (int e = 0; e < 4; ++e) {
                float2 w = *(const float2*)&Wt[k4 * 4 + e][og * 2];
                acc0 = fmaf(av[e], w.x, acc0);
                acc1 = fmaf(av[e], w.y, acc1);
            }
        }
        __syncthreads();
    }

    float x0 = acc0 + cb[og * 2], x1 = acc1 + cb[og * 2 + 1];
    float s = x0 + x1, ss = x0 * x0 + x1 * x1;
#pragma unroll
    for (int off = 32; off > 0; off >>= 1) {
        s += __shfl_xor(s, off, 64);
        ss += __shfl_xor(ss, off, 64);
    }
    float mu = s * (1.f / 128.f);
    float var = fmaxf(ss * (1.f / 128.f) - mu * mu, 0.f);
    float rs = 1.f / sqrtf(var + 1e-5f);
    int i = ibase + cc;
    float2 rv = *(const float2*)(res1 + ((size_t)(b * N1 + 2 * i)) * COUT + og * 2);
    float y0 = (x0 - mu) * rs * cg[og * 2] + cbe[og * 2];
    float y1 = (x1 - mu) * rs * cg[og * 2 + 1] + cbe[og * 2 + 1];
    float o0 = y0 / (1.f + __expf(-y0)) + rv.x;
    float o1 = y1 / (1.f + __expf(-y1)) + rv.y;
    *(float2*)(ch_out + ((size_t)(b * N2 + i)) * COUT + og * 2) = make_float2(o0, o1);
}

extern "C" void kernel_launch(void* const* d_in, const int* in_sizes, int n_in,
                              void* d_out, int out_size, void* d_ws, size_t ws_size,
                              hipStream_t stream) {
    const float* pos0 = (const float*)d_in[0];
    const float* ch0  = (const float*)d_in[1];
    const float* W1   = (const float*)d_in[2];
    const float* b1   = (const float*)d_in[3];
    const float* Wres = (const float*)d_in[4];
    const float* bres = (const float*)d_in[5];
    const float* W2   = (const float*)d_in[6];
    const float* b2   = (const float*)d_in[7];
    const float* g1   = (const float*)d_in[8];
    const float* be1  = (const float*)d_in[9];
    const float* g2   = (const float*)d_in[10];
    const float* be2  = (const float*)d_in[11];
    float* out = (float*)d_out;

    char* ws = (char*)d_ws;
    float4* pos0f = (float4*)(ws);                 // 262144 B
    float4* pos1f = (float4*)(ws + 262144);        // 131072 B
    int*    knn1  = (int*)(ws + 393216);           // 524288 B
    int*    knn2  = (int*)(ws + 917504);           // 262144 B
    float*  ch1   = (float*)(ws + 1179648);        // 4194304 B
    float*  res1  = (float*)(ws + 5373952);        // 4194304 B (total ~9.2 MB)

    float* pos_out = out;          // [2,2048,3] fp32
    float* ch_out  = out + 12288;  // [2,2048,128] fp32

    prep_kernel<<<(BATCH * N0 + 255) / 256, 256, 0, stream>>>(pos0, pos0f, pos1f, pos_out);
    knn_kernel<<<(BATCH * N1) / 4, 256, 0, stream>>>(pos0f, N0, N1, 2, knn1);
    conv1_kernel<<<(BATCH * N1) / 8, 256, 0, stream>>>(ch0, knn1, W1, b1, Wres, bres, g1, be1, ch1, res1);
    knn_kernel<<<(BATCH * N2) / 4, 256, 0, stream>>>(pos1f, N1, N2, 2, knn2);
    conv2_kernel<<<(BATCH * N2) / 4, 256, 0, stream>>>(ch1, knn2, W2, b2, g2, be2, res1, ch_out);
}

// Round 3
// 248.887 us; speedup vs baseline: 2.2420x; 2.2420x over previous
//
#include <hip/hip_runtime.h>
#include <cstdint>
#include <cstddef>

using u16 = unsigned short;
using u32 = unsigned int;
using u64 = unsigned long long;

typedef short bf16x8 __attribute__((ext_vector_type(8)));
typedef float f32x4 __attribute__((ext_vector_type(4)));

constexpr int BATCH = 2;
constexpr int N0 = 8192;
constexpr int N1 = 4096;
constexpr int N2 = 2048;
constexpr int COUT = 128;
constexpr int KNB = 16;

__device__ __forceinline__ float bf2f(u16 v) { return __uint_as_float(((u32)v) << 16); }
__device__ __forceinline__ u16 f2bf(float f) {  // round-to-nearest-even
    u32 u = __float_as_uint(f);
    return (u16)((u + 0x7fffu + ((u >> 16) & 1u)) >> 16);
}

// ---------------- prep: pos copies + bf16 conversions of ch0/W1/W2/Wres ----------------
__global__ __launch_bounds__(256)
void prep_kernel(const float* __restrict__ pos0, const float* __restrict__ ch0,
                 const float* __restrict__ W1, const float* __restrict__ W2,
                 const float* __restrict__ Wres,
                 float4* __restrict__ pos0f, float4* __restrict__ pos1f,
                 float* __restrict__ pos_out,
                 u16* __restrict__ ch0b, u16* __restrict__ W1b,
                 u16* __restrict__ W2b, u16* __restrict__ Wresb) {
    int blk = blockIdx.x, tid = threadIdx.x;
    if (blk < 64) {
        int i = blk * 256 + tid;
        int b = i >> 13, n = i & (N0 - 1);
        const float* s = pos0 + (size_t)i * 3;
        float4 v = make_float4(s[0], s[1], s[2], 0.f);
        pos0f[i] = v;
        if (!(n & 1)) pos1f[b * N1 + (n >> 1)] = v;
        if (!(n & 3)) {
            float* d = pos_out + ((size_t)b * N2 + (n >> 2)) * 3;
            d[0] = s[0]; d[1] = s[1]; d[2] = s[2];
        }
    } else if (blk < 576) {           // ch0 -> bf16 (1,048,576 elems, 8/thread)
        int e = ((blk - 64) * 256 + tid) * 8;
        float t0[8];
        *(float4*)t0 = *(const float4*)(ch0 + e);
        *(float4*)(t0 + 4) = *(const float4*)(ch0 + e + 4);
        u16 o[8];
#pragma unroll
        for (int q = 0; q < 8; ++q) o[q] = f2bf(t0[q]);
        *(uint4*)(ch0b + e) = *(uint4*)o;
    } else if (blk < 640) {           // W1 -> bf16 (131,072 elems)
        int e = ((blk - 576) * 256 + tid) * 8;
        float t0[8];
        *(float4*)t0 = *(const float4*)(W1 + e);
        *(float4*)(t0 + 4) = *(const float4*)(W1 + e + 4);
        u16 o[8];
#pragma unroll
        for (int q = 0; q < 8; ++q) o[q] = f2bf(t0[q]);
        *(uint4*)(W1b + e) = *(uint4*)o;
    } else if (blk < 768) {           // W2 -> bf16 (262,144 elems)
        int e = ((blk - 640) * 256 + tid) * 8;
        float t0[8];
        *(float4*)t0 = *(const float4*)(W2 + e);
        *(float4*)(t0 + 4) = *(const float4*)(W2 + e + 4);
        u16 o[8];
#pragma unroll
        for (int q = 0; q < 8; ++q) o[q] = f2bf(t0[q]);
        *(uint4*)(W2b + e) = *(uint4*)o;
    } else {                          // Wres[c][o] -> Wresb[o][c] bf16 (8192 elems)
        int t = (blk - 768) * 256 + tid;
        int o = t >> 6, c = t & 63;
        Wresb[o * 64 + c] = f2bf(Wres[(size_t)c * COUT + o]);
    }
}

// Distances must match the np reference bit-exactly: no FMA contraction, sequential sum.
__device__ __forceinline__ float dist2(float4 a, float4 p) {
#pragma clang fp contract(off)
    float dx = a.x - p.x;
    float dy = a.y - p.y;
    float dz = a.z - p.z;
    float s = dx * dx;
    s = s + dy * dy;
    s = s + dz * dz;
    return s;
}

// ---------------- KNN: one wave per center; list distributed across lanes 0..15 ----------------
__global__ __launch_bounds__(256)
void knn_kernel(const float4* __restrict__ pts, int npts, int nctr, int stride,
                int* __restrict__ out) {
    int wave = (blockIdx.x * blockDim.x + threadIdx.x) >> 6;
    int lane = threadIdx.x & 63;
    int b = wave / nctr;
    int j = wave - b * nctr;
    const float4* P = pts + (size_t)b * npts;
    float4 c = P[j * stride];

    // warm start: bitonic-sort first 64 points ascending across lanes; lane t holds rank t
    u64 key;
    {
        float4 p = P[lane];
        float d = dist2(c, p);
        u64 k = (((u64)__float_as_uint(d)) << 32) | (u32)lane;
#pragma unroll
        for (int kk = 2; kk <= 64; kk <<= 1) {
#pragma unroll
            for (int jj = kk >> 1; jj > 0; jj >>= 1) {
                u64 o = __shfl_xor(k, jj, 64);
                bool keepmin = (((lane & jj) == 0) == ((lane & kk) == 0));
                if (keepmin) k = (o < k) ? o : k;
                else         k = (o > k) ? o : k;
            }
        }
        key = k;
    }
    u64 cut = __shfl(key, 15, 64);

    int nstep = npts >> 6;
    for (int s = 1; s < nstep; ++s) {
        int i = (s << 6) + lane;
        float4 p = P[i];
        float d = dist2(c, p);
        u64 k = (((u64)__float_as_uint(d)) << 32) | (u32)i;
        u64 ball = __ballot(k < cut);
        while (ball) {
            int src = __ffsll((unsigned long long)ball) - 1;
            ball &= ball - 1;
            u64 nk = __shfl(k, src, 64);
            // parallel insert: lane t computes new key[t]; no-op if nk >= key[15]
            u64 prev = __shfl_up(key, 1, 64);
            if (lane == 0) prev = 0;          // -inf surrogate (keys are >= 0)
            bool lt  = nk < key;
            bool ltp = nk < prev;
            key = lt ? (ltp ? prev : nk) : key;
            cut = __shfl(key, 15, 64);
        }
    }
    if (lane < 16) out[((size_t)(b * nctr + j)) * KNB + lane] = (int)(u32)key;
}

// ---------------- conv1 (MFMA): gathered GEMM K=1024 + residual GEMM K=64, LN+SiLU ----------------
__global__ __launch_bounds__(256)
void conv1_kernel(const u16* __restrict__ ch0b, const int* __restrict__ knn1,
                  const u16* __restrict__ W1b, const u16* __restrict__ Wresb,
                  const float* __restrict__ b1, const float* __restrict__ bres,
                  const float* __restrict__ g1, const float* __restrict__ be1,
                  u16* __restrict__ ch1b, u16* __restrict__ res1b) {
    __shared__ u16 As[32][72];        // 32 rows x 64 bf16, +8 pad
    __shared__ u16 Ws[128][72];       // 128 cols x 64 bf16, +8 pad
    __shared__ int knnr[32][16];
    __shared__ float red[32][2][2];
    __shared__ float cb[128], cg[128], cbe[128], cbr[128];

    int tid = threadIdx.x;
    int b = blockIdx.x >> 7, g = blockIdx.x & 127;
    int jbase = g * 32;

    if (tid < 128) { cb[tid] = b1[tid]; cg[tid] = g1[tid]; cbe[tid] = be1[tid]; cbr[tid] = bres[tid]; }
    {   // 512 knn ints, 2 per thread
        int r = tid >> 3, k2 = (tid & 7) * 2;
        const int* src = knn1 + ((size_t)(b * N1 + jbase + r)) * KNB + k2;
        knnr[r][k2] = src[0]; knnr[r][k2 + 1] = src[1];
    }
    __syncthreads();

    int w = tid >> 6, lane = tid & 63, quad = lane >> 4, l15 = lane & 15;
    int wrow = (w & 1) * 16, wcol = (w >> 1) * 64;
    int ar = tid >> 3, ap = tid & 7;      // A staging: row, 16B chunk
    int wn = tid >> 1, wh = tid & 1;      // W staging: col row, half

    f32x4 acc[4] = {{0,0,0,0},{0,0,0,0},{0,0,0,0},{0,0,0,0}};
    f32x4 racc[4] = {{0,0,0,0},{0,0,0,0},{0,0,0,0},{0,0,0,0}};

    for (int kn = 0; kn < 16; ++kn) {
        {   // stage A: gathered neighbor-kn channels (bf16), 128B per row
            int idx = knnr[ar][kn];
            *(uint4*)&As[ar][ap * 8] = *((const uint4*)(ch0b + ((size_t)(b * N0 + idx)) * 64) + ap);
        }
        {   // stage W: W1b[n][kn*64 .. +64)
            const uint4* s4 = (const uint4*)(W1b + (size_t)wn * 1024 + kn * 64 + wh * 32);
            uint4* d4 = (uint4*)&Ws[wn][wh * 32];
            d4[0] = s4[0]; d4[1] = s4[1]; d4[2] = s4[2]; d4[3] = s4[3];
        }
        __syncthreads();
#pragma unroll
        for (int ks = 0; ks < 2; ++ks) {
            bf16x8 af = *(const bf16x8*)&As[wrow + l15][ks * 32 + quad * 8];
#pragma unroll
            for (int nt = 0; nt < 4; ++nt) {
                bf16x8 bfr = *(const bf16x8*)&Ws[wcol + nt * 16 + l15][ks * 32 + quad * 8];
                acc[nt] = __builtin_amdgcn_mfma_f32_16x16x32_bf16(af, bfr, acc[nt], 0, 0, 0);
            }
        }
        __syncthreads();
    }
    {   // residual chunk: A = center rows (idx=2*j), W = Wresb[o][c]
        *(uint4*)&As[ar][ap * 8] = *((const uint4*)(ch0b + ((size_t)(b * N0 + 2 * (jbase + ar))) * 64) + ap);
        const uint4* s4 = (const uint4*)(Wresb + (size_t)wn * 64 + wh * 32);
        uint4* d4 = (uint4*)&Ws[wn][wh * 32];
        d4[0] = s4[0]; d4[1] = s4[1]; d4[2] = s4[2]; d4[3] = s4[3];
        __syncthreads();
#pragma unroll
        for (int ks = 0; ks < 2; ++ks) {
            bf16x8 af = *(const bf16x8*)&As[wrow + l15][ks * 32 + quad * 8];
#pragma unroll
            for (int nt = 0; nt < 4; ++nt) {
                bf16x8 bfr = *(const bf16x8*)&Ws[wcol + nt * 16 + l15][ks * 32 + quad * 8];
                racc[nt] = __builtin_amdgcn_mfma_f32_16x16x32_bf16(af, bfr, racc[nt], 0, 0, 0);
            }
        }
    }

    // epilogue: bias + LN(+SiLU) on conv acc; bias on residual; both stored bf16
    float x[4][4], s[4] = {0,0,0,0}, ss[4] = {0,0,0,0};
#pragma unroll
    for (int reg = 0; reg < 4; ++reg)
#pragma unroll
        for (int nt = 0; nt < 4; ++nt) {
            int col = wcol + nt * 16 + l15;
            float v = acc[nt][reg] + cb[col];
            x[nt][reg] = v;
            s[reg] += v; ss[reg] += v * v;
        }
#pragma unroll
    for (int m = 1; m < 16; m <<= 1)
#pragma unroll
        for (int reg = 0; reg < 4; ++reg) {
            s[reg] += __shfl_xor(s[reg], m, 64);
            ss[reg] += __shfl_xor(ss[reg], m, 64);
        }
    if (l15 == 0) {
#pragma unroll
        for (int reg = 0; reg < 4; ++reg) {
            red[wrow + quad * 4 + reg][w >> 1][0] = s[reg];
            red[wrow + quad * 4 + reg][w >> 1][1] = ss[reg];
        }
    }
    __syncthreads();
    float mu[4], rs[4];
#pragma unroll
    for (int reg = 0; reg < 4; ++reg) {
        int row = wrow + quad * 4 + reg;
        float S = red[row][0][0] + red[row][1][0];
        float SS = red[row][0][1] + red[row][1][1];
        mu[reg] = S * (1.f / 128.f);
        float var = fmaxf(SS * (1.f / 128.f) - mu[reg] * mu[reg], 0.f);
        rs[reg] = 1.f / sqrtf(var + 1e-5f);
    }
#pragma unroll
    for (int nt = 0; nt < 4; ++nt)
#pragma unroll
        for (int reg = 0; reg < 4; ++reg) {
            int col = wcol + nt * 16 + l15;
            int row = wrow + quad * 4 + reg;
            size_t off = ((size_t)(b * N1 + jbase + row)) * COUT + col;
            float y = (x[nt][reg] - mu[reg]) * rs[reg] * cg[col] + cbe[col];
            ch1b[off] = f2bf(y / (1.f + __expf(-y)));
            res1b[off] = f2bf(racc[nt][reg] + cbr[col]);
        }
}

// ---------------- conv2 (MFMA): gathered GEMM K=2048 + LN + SiLU + res-add -> fp32 out ----------------
__global__ __launch_bounds__(256)
void conv2_kernel(const u16* __restrict__ ch1b, const int* __restrict__ knn2,
                  const u16* __restrict__ W2b, const float* __restrict__ b2,
                  const float* __restrict__ g2, const float* __restrict__ be2,
                  const u16* __restrict__ res1b, float* __restrict__ ch_out) {
    __shared__ u16 As[16][136];       // 16 rows x 128 bf16, +8 pad
    __shared__ u16 Ws[128][136];
    __shared__ int knnr[16][16];
    __shared__ float red[16][4][2];
    __shared__ float cb[128], cg[128], cbe[128];

    int tid = threadIdx.x;
    int b = blockIdx.x >> 7, g = blockIdx.x & 127;
    int ibase = g * 16;

    if (tid < 128) { cb[tid] = b2[tid]; cg[tid] = g2[tid]; cbe[tid] = be2[tid]; }
    if (tid < 128) {   // 256 knn ints, 2 per thread (first 128 threads)
        int r = tid >> 3, k2 = (tid & 7) * 2;
        const int* src = knn2 + ((size_t)(b * N2 + ibase + r)) * KNB + k2;
        knnr[r][k2] = src[0]; knnr[r][k2 + 1] = src[1];
    }
    __syncthreads();

    int w = tid >> 6, lane = tid & 63, quad = lane >> 4, l15 = lane & 15;
    int wcol = w * 32;
    int ar = tid >> 4, ap = tid & 15;
    int wn = tid >> 1, wh = tid & 1;

    f32x4 acc[2] = {{0,0,0,0},{0,0,0,0}};

    for (int kn = 0; kn < 16; ++kn) {
        {   // stage A: 16 rows x 256B
            int idx = knnr[ar][kn];
            *(uint4*)&As[ar][ap * 8] = *((const uint4*)(ch1b + ((size_t)(b * N1 + idx)) * COUT) + ap);
        }
        {   // stage W: W2b[n][kn*128 .. +128), 128B per thread
            const uint4* s4 = (const uint4*)(W2b + (size_t)wn * 2048 + kn * 128 + wh * 64);
            uint4* d4 = (uint4*)&Ws[wn][wh * 64];
#pragma unroll
            for (int q = 0; q < 8; ++q) d4[q] = s4[q];
        }
        __syncthreads();
#pragma unroll
        for (int ks = 0; ks < 4; ++ks) {
            bf16x8 af = *(const bf16x8*)&As[l15][ks * 32 + quad * 8];
#pragma unroll
            for (int nt = 0; nt < 2; ++nt) {
                bf16x8 bfr = *(const bf16x8*)&Ws[wcol + nt * 16 + l15][ks * 32 + quad * 8];
                acc[nt] = __builtin_amdgcn_mfma_f32_16x16x32_bf16(af, bfr, acc[nt], 0, 0, 0);
            }
        }
        __syncthreads();
    }

    float x[2][4], s[4] = {0,0,0,0}, ss[4] = {0,0,0,0};
#pragma unroll
    for (int reg = 0; reg < 4; ++reg)
#pragma unroll
        for (int nt = 0; nt < 2; ++nt) {
            int col = wcol + nt * 16 + l15;
            float v = acc[nt][reg] + cb[col];
            x[nt][reg] = v;
            s[reg] += v; ss[reg] += v * v;
        }
#pragma unroll
    for (int m = 1; m < 16; m <<= 1)
#pragma unroll
        for (int reg = 0; reg < 4; ++reg) {
            s[reg] += __shfl_xor(s[reg], m, 64);
            ss[reg] += __shfl_xor(ss[reg], m, 64);
        }
    if (l15 == 0) {
#pragma unroll
        for (int reg = 0; reg < 4; ++reg) {
            red[quad * 4 + reg][w][0] = s[reg];
            red[quad * 4 + reg][w][1] = ss[reg];
        }
    }
    __syncthreads();
    float mu[4], rs[4];
#pragma unroll
    for (int reg = 0; reg < 4; ++reg) {
        int row = quad * 4 + reg;
        float S = red[row][0][0] + red[row][1][0] + red[row][2][0] + red[row][3][0];
        float SS = red[row][0][1] + red[row][1][1] + red[row][2][1] + red[row][3][1];
        mu[reg] = S * (1.f / 128.f);
        float var = fmaxf(SS * (1.f / 128.f) - mu[reg] * mu[reg], 0.f);
        rs[reg] = 1.f / sqrtf(var + 1e-5f);
    }
#pragma unroll
    for (int nt = 0; nt < 2; ++nt)
#pragma unroll
        for (int reg = 0; reg < 4; ++reg) {
            int col = wcol + nt * 16 + l15;
            int row = quad * 4 + reg;
            int i = ibase + row;
            float y = (x[nt][reg] - mu[reg]) * rs[reg] * cg[col] + cbe[col];
            float sl = y / (1.f + __expf(-y));
            float rv = bf2f(res1b[((size_t)(b * N1 + 2 * i)) * COUT + col]);
            ch_out[((size_t)(b * N2 + i)) * COUT + col] = sl + rv;
        }
}

extern "C" void kernel_launch(void* const* d_in, const int* in_sizes, int n_in,
                              void* d_out, int out_size, void* d_ws, size_t ws_size,
                              hipStream_t stream) {
    const float* pos0 = (const float*)d_in[0];
    const float* ch0  = (const float*)d_in[1];
    const float* W1   = (const float*)d_in[2];
    const float* b1   = (const float*)d_in[3];
    const float* Wres = (const float*)d_in[4];
    const float* bres = (const float*)d_in[5];
    const float* W2   = (const float*)d_in[6];
    const float* b2   = (const float*)d_in[7];
    const float* g1   = (const float*)d_in[8];
    const float* be1  = (const float*)d_in[9];
    const float* g2   = (const float*)d_in[10];
    const float* be2  = (const float*)d_in[11];
    float* out = (float*)d_out;

    char* ws = (char*)d_ws;
    float4* pos0f = (float4*)(ws);                  // 262144
    float4* pos1f = (float4*)(ws + 262144);         // 131072
    int*    knn1  = (int*)(ws + 393216);            // 524288
    int*    knn2  = (int*)(ws + 917504);            // 262144
    u16*    ch0b  = (u16*)(ws + 1179648);           // 2097152
    u16*    W1b   = (u16*)(ws + 3276800);           // 262144
    u16*    W2b   = (u16*)(ws + 3538944);           // 524288
    u16*    Wresb = (u16*)(ws + 4063232);           // 16384
    u16*    ch1b  = (u16*)(ws + 4079616);           // 2097152
    u16*    res1b = (u16*)(ws + 6176768);           // 2097152  (total ~8.27 MB)

    float* pos_out = out;          // [2,2048,3] fp32
    float* ch_out  = out + 12288;  // [2,2048,128] fp32

    prep_kernel<<<800, 256, 0, stream>>>(pos0, ch0, W1, W2, Wres,
                                         pos0f, pos1f, pos_out, ch0b, W1b, W2b, Wresb);
    knn_kernel<<<2048, 256, 0, stream>>>(pos0f, N0, N1, 2, knn1);
    conv1_kernel<<<256, 256, 0, stream>>>(ch0b, knn1, W1b, Wresb, b1, bres, g1, be1, ch1b, res1b);
    knn_kernel<<<1024, 256, 0, stream>>>(pos1f, N1, N2, 2, knn2);
    conv2_kernel<<<256, 256, 0, stream>>>(ch1b, knn2, W2b, b2, g2, be2, res1b, ch_out);
}

// Round 5
// 238.925 us; speedup vs baseline: 2.3355x; 1.0417x over previous
//
#include <hip/hip_runtime.h>
#include <cstdint>
#include <cstddef>

using u16 = unsigned short;
using u32 = unsigned int;
using u64 = unsigned long long;

typedef short bf16x8 __attribute__((ext_vector_type(8)));
typedef float f32x4 __attribute__((ext_vector_type(4)));

constexpr int BATCH = 2;
constexpr int N0 = 8192;
constexpr int N1 = 4096;
constexpr int N2 = 2048;
constexpr int COUT = 128;
constexpr int KNB = 16;

__device__ __forceinline__ float bf2f(u16 v) { return __uint_as_float(((u32)v) << 16); }
__device__ __forceinline__ u16 f2bf(float f) {  // round-to-nearest-even
    u32 u = __float_as_uint(f);
    return (u16)((u + 0x7fffu + ((u >> 16) & 1u)) >> 16);
}
__device__ __forceinline__ void cvt8(const float* __restrict__ src, u16* __restrict__ dst, int e) {
    float t0[8];
    *(float4*)t0 = *(const float4*)(src + e);
    *(float4*)(t0 + 4) = *(const float4*)(src + e + 4);
    u16 o[8];
#pragma unroll
    for (int q = 0; q < 8; ++q) o[q] = f2bf(t0[q]);
    *(uint4*)(dst + e) = *(uint4*)o;
}

// Distances must match the np reference bit-exactly: no FMA contraction, sequential sum.
__device__ __forceinline__ float dist2s(float cx, float cy, float cz,
                                        float px, float py, float pz) {
#pragma clang fp contract(off)
    float dx = cx - px;
    float dy = cy - py;
    float dz = cz - pz;
    float s = dx * dx;
    s = s + dy * dy;
    s = s + dz * dz;
    return s;
}

// ---------------- KNN body: one wave handles TWO centers (ILP); sorted-16 list
// distributed across lanes 0..15; exact order + low-index tie-break via u64 key ----------------
__device__ __forceinline__ void knn_body(const float* __restrict__ pos, int pstride,
                                         int npts, int nctr, int* __restrict__ out,
                                         int wave, int lane) {
    int pairs = nctr >> 1;
    int b = wave / pairs;
    int pj = wave - b * pairs;
    int j0 = 2 * pj, j1 = j0 + 1;
    const float* P = pos + (size_t)b * N0 * 3;
    const float* c0p = P + (size_t)(2 * j0) * pstride;
    const float* c1p = P + (size_t)(2 * j1) * pstride;
    float c0x = c0p[0], c0y = c0p[1], c0z = c0p[2];
    float c1x = c1p[0], c1y = c1p[1], c1z = c1p[2];

    u64 key0, key1;
    {   // warm start: bitonic-sort first 64 points for both centers (interleaved)
        const float* pp = P + (size_t)lane * pstride;
        float px = pp[0], py = pp[1], pz = pp[2];
        u64 k0 = (((u64)__float_as_uint(dist2s(c0x, c0y, c0z, px, py, pz))) << 32) | (u32)lane;
        u64 k1 = (((u64)__float_as_uint(dist2s(c1x, c1y, c1z, px, py, pz))) << 32) | (u32)lane;
#pragma unroll
        for (int kk = 2; kk <= 64; kk <<= 1) {
#pragma unroll
            for (int jj = kk >> 1; jj > 0; jj >>= 1) {
                u64 o0 = __shfl_xor(k0, jj, 64);
                u64 o1 = __shfl_xor(k1, jj, 64);
                bool keepmin = (((lane & jj) == 0) == ((lane & kk) == 0));
                k0 = keepmin ? ((o0 < k0) ? o0 : k0) : ((o0 > k0) ? o0 : k0);
                k1 = keepmin ? ((o1 < k1) ? o1 : k1) : ((o1 > k1) ? o1 : k1);
            }
        }
        key0 = k0; key1 = k1;
    }
    u64 cut0 = __shfl(key0, 15, 64);
    u64 cut1 = __shfl(key1, 15, 64);

    int nstep = npts >> 6;
    const float* pp = P + (size_t)(64 + lane) * pstride;
    float pnx = pp[0], pny = pp[1], pnz = pp[2];
    for (int s = 1; s < nstep; ++s) {
        float px = pnx, py = pny, pz = pnz;
        int nx = (s + 1 < nstep) ? ((s + 1) << 6) : (s << 6);
        const float* np_ = P + (size_t)(nx + lane) * pstride;
        pnx = np_[0]; pny = np_[1]; pnz = np_[2];
        int i = (s << 6) + lane;
        u64 k0 = (((u64)__float_as_uint(dist2s(c0x, c0y, c0z, px, py, pz))) << 32) | (u32)i;
        u64 k1 = (((u64)__float_as_uint(dist2s(c1x, c1y, c1z, px, py, pz))) << 32) | (u32)i;
        u64 ball0 = __ballot(k0 < cut0);
        u64 ball1 = __ballot(k1 < cut1);
        bool any0 = ball0 != 0, any1 = ball1 != 0;
        while (ball0 | ball1) {   // two independent chains -> ILP
            if (ball0) {
                int src = __ffsll((unsigned long long)ball0) - 1;
                ball0 &= ball0 - 1;
                u64 nk = __shfl(k0, src, 64);
                u64 prev = __shfl_up(key0, 1, 64);
                if (lane == 0) prev = 0;
                key0 = (nk < key0) ? ((nk < prev) ? prev : nk) : key0;
            }
            if (ball1) {
                int src = __ffsll((unsigned long long)ball1) - 1;
                ball1 &= ball1 - 1;
                u64 nk = __shfl(k1, src, 64);
                u64 prev = __shfl_up(key1, 1, 64);
                if (lane == 0) prev = 0;
                key1 = (nk < key1) ? ((nk < prev) ? prev : nk) : key1;
            }
        }
        if (any0) cut0 = __shfl(key0, 15, 64);
        if (any1) cut1 = __shfl(key1, 15, 64);
    }
    if (lane < 16) {
        out[((size_t)(b * nctr + j0)) * KNB + lane] = (int)(u32)key0;
        out[((size_t)(b * nctr + j1)) * KNB + lane] = (int)(u32)key1;
    }
}

// ---------------- dispatch 1: knn1 (1024 blocks) + prep conversions (752 blocks) ----------------
__global__ __launch_bounds__(256)
void knn1_prep_kernel(const float* __restrict__ pos0, const float* __restrict__ ch0,
                      const float* __restrict__ W1, const float* __restrict__ W2,
                      const float* __restrict__ Wres,
                      int* __restrict__ knn1, u16* __restrict__ ch0b,
                      u16* __restrict__ W1b, u16* __restrict__ W2b,
                      u16* __restrict__ Wresb, float* __restrict__ pos_out) {
    int blk = blockIdx.x, tid = threadIdx.x;
    if (blk < 1024) {
        knn_body(pos0, 3, N0, N1, knn1, blk * 4 + (tid >> 6), tid & 63);
    } else if (blk < 1536) {          // ch0 -> bf16 (1,048,576 elems)
        cvt8(ch0, ch0b, ((blk - 1024) * 256 + tid) * 8);
    } else if (blk < 1600) {          // W1 -> bf16 (131,072)
        cvt8(W1, W1b, ((blk - 1536) * 256 + tid) * 8);
    } else if (blk < 1728) {          // W2 -> bf16 (262,144)
        cvt8(W2, W2b, ((blk - 1600) * 256 + tid) * 8);
    } else if (blk < 1760) {          // Wres[c][o] -> Wresb[o][c] bf16 (8192 elems, 32 blocks)
        int t = (blk - 1728) * 256 + tid;
        int o = t >> 6, c = t & 63;
        Wresb[o * 64 + c] = f2bf(Wres[(size_t)c * COUT + o]);
    } else {                          // pos_out copy: 4096 rows (16 blocks)
        int t = (blk - 1760) * 256 + tid;
        int b = t >> 11, r = t & 2047;
        const float* s = pos0 + ((size_t)(b * N0 + r * 4)) * 3;
        float* d = pos_out + ((size_t)(b * N2 + r)) * 3;
        d[0] = s[0]; d[1] = s[1]; d[2] = s[2];
    }
}

// ---------------- dispatch 2: knn2 (512 blocks) + conv1 MFMA (256 blocks) ----------------
__global__ __launch_bounds__(256)
void knn2_conv1_kernel(const float* __restrict__ pos0, int* __restrict__ knn2,
                       const u16* __restrict__ ch0b, const int* __restrict__ knn1,
                       const u16* __restrict__ W1b, const u16* __restrict__ Wresb,
                       const float* __restrict__ b1, const float* __restrict__ bres,
                       const float* __restrict__ g1, const float* __restrict__ be1,
                       u16* __restrict__ ch1b, u16* __restrict__ res1b) {
    __shared__ u16 As[32][72];        // 32 rows x 64 bf16, +8 pad
    __shared__ u16 Ws[128][72];       // 128 cols x 64 bf16, +8 pad
    __shared__ int knnr[32][16];
    __shared__ float red[32][2][2];
    __shared__ float cb[128], cg[128], cbe[128], cbr[128];

    int tid = threadIdx.x;
    if (blockIdx.x < 512) {   // knn2: candidates = level-1 rows (stride 6 floats in pos0)
        knn_body(pos0, 6, N1, N2, knn2, blockIdx.x * 4 + (tid >> 6), tid & 63);
        return;
    }
    int blk = blockIdx.x - 512;
    int b = blk >> 7, g = blk & 127;
    int jbase = g * 32;

    if (tid < 128) { cb[tid] = b1[tid]; cg[tid] = g1[tid]; cbe[tid] = be1[tid]; cbr[tid] = bres[tid]; }
    {   // 512 knn ints, 2 per thread
        int r = tid >> 3, k2 = (tid & 7) * 2;
        const int* src = knn1 + ((size_t)(b * N1 + jbase + r)) * KNB + k2;
        knnr[r][k2] = src[0]; knnr[r][k2 + 1] = src[1];
    }
    __syncthreads();

    int w = tid >> 6, lane = tid & 63, quad = lane >> 4, l15 = lane & 15;
    int wrow = (w & 1) * 16, wcol = (w >> 1) * 64;
    int ar = tid >> 3, ap = tid & 7;      // A staging: row, 16B chunk
    int wn = tid >> 1, wh = tid & 1;      // W staging: col, half

    f32x4 acc[4] = {{0,0,0,0},{0,0,0,0},{0,0,0,0},{0,0,0,0}};
    f32x4 racc[4] = {{0,0,0,0},{0,0,0,0},{0,0,0,0},{0,0,0,0}};

    // software pipeline: prefetch chunk 0
    uint4 aR = *((const uint4*)(ch0b + ((size_t)(b * N0 + knnr[ar][0])) * 64) + ap);
    uint4 wR[4];
    {
        const uint4* s4 = (const uint4*)(W1b + (size_t)wn * 1024 + wh * 32);
        wR[0] = s4[0]; wR[1] = s4[1]; wR[2] = s4[2]; wR[3] = s4[3];
    }
    for (int kn = 0; kn < 17; ++kn) {     // 16 neighbor chunks + 1 residual chunk
        *(uint4*)&As[ar][ap * 8] = aR;
        uint4* d4 = (uint4*)&Ws[wn][wh * 32];
        d4[0] = wR[0]; d4[1] = wR[1]; d4[2] = wR[2]; d4[3] = wR[3];
        __syncthreads();
        if (kn < 16) {  // prefetch next chunk (kn==15 -> residual sources)
            int nidx = (kn < 15) ? knnr[ar][kn + 1] : 2 * (jbase + ar);
            aR = *((const uint4*)(ch0b + ((size_t)(b * N0 + nidx)) * 64) + ap);
            const uint4* s4 = (kn < 15)
                ? (const uint4*)(W1b + (size_t)wn * 1024 + (kn + 1) * 64 + wh * 32)
                : (const uint4*)(Wresb + (size_t)wn * 64 + wh * 32);
            wR[0] = s4[0]; wR[1] = s4[1]; wR[2] = s4[2]; wR[3] = s4[3];
        }
        if (kn < 16) {
#pragma unroll
            for (int ks = 0; ks < 2; ++ks) {
                bf16x8 af = *(const bf16x8*)&As[wrow + l15][ks * 32 + quad * 8];
#pragma unroll
                for (int nt = 0; nt < 4; ++nt) {
                    bf16x8 bfr = *(const bf16x8*)&Ws[wcol + nt * 16 + l15][ks * 32 + quad * 8];
                    acc[nt] = __builtin_amdgcn_mfma_f32_16x16x32_bf16(af, bfr, acc[nt], 0, 0, 0);
                }
            }
        } else {
#pragma unroll
            for (int ks = 0; ks < 2; ++ks) {
                bf16x8 af = *(const bf16x8*)&As[wrow + l15][ks * 32 + quad * 8];
#pragma unroll
                for (int nt = 0; nt < 4; ++nt) {
                    bf16x8 bfr = *(const bf16x8*)&Ws[wcol + nt * 16 + l15][ks * 32 + quad * 8];
                    racc[nt] = __builtin_amdgcn_mfma_f32_16x16x32_bf16(af, bfr, racc[nt], 0, 0, 0);
                }
            }
        }
        __syncthreads();
    }

    // epilogue: bias + LN(+SiLU) on conv acc; bias on residual; both stored bf16
    float x[4][4], s[4] = {0,0,0,0}, ss[4] = {0,0,0,0};
#pragma unroll
    for (int reg = 0; reg < 4; ++reg)
#pragma unroll
        for (int nt = 0; nt < 4; ++nt) {
            int col = wcol + nt * 16 + l15;
            float v = acc[nt][reg] + cb[col];
            x[nt][reg] = v;
            s[reg] += v; ss[reg] += v * v;
        }
#pragma unroll
    for (int m = 1; m < 16; m <<= 1)
#pragma unroll
        for (int reg = 0; reg < 4; ++reg) {
            s[reg] += __shfl_xor(s[reg], m, 64);
            ss[reg] += __shfl_xor(ss[reg], m, 64);
        }
    if (l15 == 0) {
#pragma unroll
        for (int reg = 0; reg < 4; ++reg) {
            red[wrow + quad * 4 + reg][w >> 1][0] = s[reg];
            red[wrow + quad * 4 + reg][w >> 1][1] = ss[reg];
        }
    }
    __syncthreads();
    float mu[4], rs[4];
#pragma unroll
    for (int reg = 0; reg < 4; ++reg) {
        int row = wrow + quad * 4 + reg;
        float S = red[row][0][0] + red[row][1][0];
        float SS = red[row][0][1] + red[row][1][1];
        mu[reg] = S * (1.f / 128.f);
        float var = fmaxf(SS * (1.f / 128.f) - mu[reg] * mu[reg], 0.f);
        rs[reg] = 1.f / sqrtf(var + 1e-5f);
    }
#pragma unroll
    for (int nt = 0; nt < 4; ++nt)
#pragma unroll
        for (int reg = 0; reg < 4; ++reg) {
            int col = wcol + nt * 16 + l15;
            int row = wrow + quad * 4 + reg;
            size_t off = ((size_t)(b * N1 + jbase + row)) * COUT + col;
            float y = (x[nt][reg] - mu[reg]) * rs[reg] * cg[col] + cbe[col];
            ch1b[off] = f2bf(y / (1.f + __expf(-y)));
            res1b[off] = f2bf(racc[nt][reg] + cbr[col]);
        }
}

// ---------------- dispatch 3: conv2 MFMA K=2048 + LN + SiLU + res-add -> fp32 out ----------------
__global__ __launch_bounds__(256)
void conv2_kernel(const u16* __restrict__ ch1b, const int* __restrict__ knn2,
                  const u16* __restrict__ W2b, const float* __restrict__ b2,
                  const float* __restrict__ g2, const float* __restrict__ be2,
                  const u16* __restrict__ res1b, float* __restrict__ ch_out) {
    __shared__ u16 As[16][136];       // 16 rows x 128 bf16, +8 pad
    __shared__ u16 Ws[128][136];
    __shared__ int knnr[16][16];
    __shared__ float red[16][4][2];
    __shared__ float cb[128], cg[128], cbe[128];

    int tid = threadIdx.x;
    int b = blockIdx.x >> 7, g = blockIdx.x & 127;
    int ibase = g * 16;

    if (tid < 128) { cb[tid] = b2[tid]; cg[tid] = g2[tid]; cbe[tid] = be2[tid]; }
    if (tid < 128) {
        int r = tid >> 3, k2 = (tid & 7) * 2;
        const int* src = knn2 + ((size_t)(b * N2 + ibase + r)) * KNB + k2;
        knnr[r][k2] = src[0]; knnr[r][k2 + 1] = src[1];
    }
    __syncthreads();

    int w = tid >> 6, lane = tid & 63, quad = lane >> 4, l15 = lane & 15;
    int wcol = w * 32;
    int ar = tid >> 4, ap = tid & 15;
    int wn = tid >> 1, wh = tid & 1;

    f32x4 acc[2] = {{0,0,0,0},{0,0,0,0}};

    uint4 aR = *((const uint4*)(ch1b + ((size_t)(b * N1 + knnr[ar][0])) * COUT) + ap);
    uint4 wR[8];
    {
        const uint4* s4 = (const uint4*)(W2b + (size_t)wn * 2048 + wh * 64);
#pragma unroll
        for (int q = 0; q < 8; ++q) wR[q] = s4[q];
    }
    for (int kn = 0; kn < 16; ++kn) {
        *(uint4*)&As[ar][ap * 8] = aR;
        uint4* d4 = (uint4*)&Ws[wn][wh * 64];
#pragma unroll
        for (int q = 0; q < 8; ++q) d4[q] = wR[q];
        __syncthreads();
        if (kn < 15) {
            aR = *((const uint4*)(ch1b + ((size_t)(b * N1 + knnr[ar][kn + 1])) * COUT) + ap);
            const uint4* s4 = (const uint4*)(W2b + (size_t)wn * 2048 + (kn + 1) * 128 + wh * 64);
#pragma unroll
            for (int q = 0; q < 8; ++q) wR[q] = s4[q];
        }
#pragma unroll
        for (int ks = 0; ks < 4; ++ks) {
            bf16x8 af = *(const bf16x8*)&As[l15][ks * 32 + quad * 8];
#pragma unroll
            for (int nt = 0; nt < 2; ++nt) {
                bf16x8 bfr = *(const bf16x8*)&Ws[wcol + nt * 16 + l15][ks * 32 + quad * 8];
                acc[nt] = __builtin_amdgcn_mfma_f32_16x16x32_bf16(af, bfr, acc[nt], 0, 0, 0);
            }
        }
        __syncthreads();
    }

    float x[2][4], s[4] = {0,0,0,0}, ss[4] = {0,0,0,0};
#pragma unroll
    for (int reg = 0; reg < 4; ++reg)
#pragma unroll
        for (int nt = 0; nt < 2; ++nt) {
            int col = wcol + nt * 16 + l15;
            float v = acc[nt][reg] + cb[col];
            x[nt][reg] = v;
            s[reg] += v; ss[reg] += v * v;
        }
#pragma unroll
    for (int m = 1; m < 16; m <<= 1)
#pragma unroll
        for (int reg = 0; reg < 4; ++reg) {
            s[reg] += __shfl_xor(s[reg], m, 64);
            ss[reg] += __shfl_xor(ss[reg], m, 64);
        }
    if (l15 == 0) {
#pragma unroll
        for (int reg = 0; reg < 4; ++reg) {
            red[quad * 4 + reg][w][0] = s[reg];
            red[quad * 4 + reg][w][1] = ss[reg];
        }
    }
    __syncthreads();
    float mu[4], rs[4];
#pragma unroll
    for (int reg = 0; reg < 4; ++reg) {
        int row = quad * 4 + reg;
        float S = red[row][0][0] + red[row][1][0] + red[row][2][0] + red[row][3][0];
        float SS = red[row][0][1] + red[row][1][1] + red[row][2][1] + red[row][3][1];
        mu[reg] = S * (1.f / 128.f);
        float var = fmaxf(SS * (1.f / 128.f) - mu[reg] * mu[reg], 0.f);
        rs[reg] = 1.f / sqrtf(var + 1e-5f);
    }
#pragma unroll
    for (int nt = 0; nt < 2; ++nt)
#pragma unroll
        for (int reg = 0; reg < 4; ++reg) {
            int col = wcol + nt * 16 + l15;
            int row = quad * 4 + reg;
            int i = ibase + row;
            float y = (x[nt][reg] - mu[reg]) * rs[reg] * cg[col] + cbe[col];
            float sl = y / (1.f + __expf(-y));
            float rv = bf2f(res1b[((size_t)(b * N1 + 2 * i)) * COUT + col]);
            ch_out[((size_t)(b * N2 + i)) * COUT + col] = sl + rv;
        }
}

extern "C" void kernel_launch(void* const* d_in, const int* in_sizes, int n_in,
                              void* d_out, int out_size, void* d_ws, size_t ws_size,
                              hipStream_t stream) {
    const float* pos0 = (const float*)d_in[0];
    const float* ch0  = (const float*)d_in[1];
    const float* W1   = (const float*)d_in[2];
    const float* b1   = (const float*)d_in[3];
    const float* Wres = (const float*)d_in[4];
    const float* bres = (const float*)d_in[5];
    const float* W2   = (const float*)d_in[6];
    const float* b2   = (const float*)d_in[7];
    const float* g1   = (const float*)d_in[8];
    const float* be1  = (const float*)d_in[9];
    const float* g2   = (const float*)d_in[10];
    const float* be2  = (const float*)d_in[11];
    float* out = (float*)d_out;

    char* ws = (char*)d_ws;
    int*  knn1  = (int*)(ws);                      // 524288
    int*  knn2  = (int*)(ws + 524288);             // 262144
    u16*  ch0b  = (u16*)(ws + 786432);             // 2097152
    u16*  W1b   = (u16*)(ws + 2883584);            // 262144
    u16*  W2b   = (u16*)(ws + 3145728);            // 524288
    u16*  Wresb = (u16*)(ws + 3670016);            // 16384
    u16*  ch1b  = (u16*)(ws + 3686400);            // 2097152
    u16*  res1b = (u16*)(ws + 5783552);            // 2097152  (total ~7.9 MB)

    float* pos_out = out;          // [2,2048,3] fp32
    float* ch_out  = out + 12288;  // [2,2048,128] fp32

    knn1_prep_kernel<<<1776, 256, 0, stream>>>(pos0, ch0, W1, W2, Wres,
                                               knn1, ch0b, W1b, W2b, Wresb, pos_out);
    knn2_conv1_kernel<<<768, 256, 0, stream>>>(pos0, knn2, ch0b, knn1, W1b, Wresb,
                                               b1, bres, g1, be1, ch1b, res1b);
    conv2_kernel<<<256, 256, 0, stream>>>(ch1b, knn2, W2b, b2, g2, be2, res1b, ch_out);
}